// Round 1
// baseline (674.471 us; speedup 1.0000x reference)
//
// GLM4 attention block (B=1, L=2048, HID=4096, H=32, KV=2, D=128, ROT=64) on MI355X.
// Round 1: bf16-MFMA pipeline.
//   cast x -> bf16 ; transpose+cast W* -> (N,K) bf16
//   gemm_bt (m97-style 128x128 tile, BK=64, global_load_lds 16B) for Q / KV / O proj
//   bias+RoPE+relayout kernels ; flash attention (4 waves, QB=64, KVB=32, online softmax)
// Workspace use: ~138 MiB.
#include <hip/hip_runtime.h>
#include <stdint.h>

#define L_SEQ 2048
#define HID   4096
#define NH    32
#define NKV   2
#define DH    128
#define QSCALE 0.088388347648318447f   // 128^-0.5

typedef __bf16 bf16x8 __attribute__((ext_vector_type(8)));
typedef float  f32x4  __attribute__((ext_vector_type(4)));

__device__ __forceinline__ unsigned short f2bf(float f) {
  union { float f; unsigned u; } cv; cv.f = f;
  unsigned u = cv.u;
  return (unsigned short)((u + 0x7fffu + ((u >> 16) & 1u)) >> 16);   // RNE, finite-only
}

// async global->LDS, 16B per lane; LDS dest = wave-uniform base + lane*16
#define GLL16(gsrc, ldst)                                                              \
  __builtin_amdgcn_global_load_lds(                                                    \
      (const __attribute__((address_space(1))) unsigned int*)(gsrc),                   \
      (__attribute__((address_space(3))) unsigned int*)(ldst), 16, 0, 0)

// ---------------------------------------------------------------- casts
__global__ __launch_bounds__(256) void cast_bf16_kernel(const float* __restrict__ in,
                                                        unsigned short* __restrict__ out,
                                                        int n4) {
  int i = blockIdx.x * 256 + threadIdx.x;
  if (i >= n4) return;
  float4 v = reinterpret_cast<const float4*>(in)[i];
  ushort4 o;
  o.x = f2bf(v.x); o.y = f2bf(v.y); o.z = f2bf(v.z); o.w = f2bf(v.w);
  reinterpret_cast<ushort4*>(out)[i] = o;
}

// in: (R,C) fp32 row-major -> out: (C,R) bf16 row-major
__global__ __launch_bounds__(256) void transpose_cast_kernel(const float* __restrict__ in,
                                                             unsigned short* __restrict__ out,
                                                             int R, int C) {
  __shared__ float tile[32][33];
  int c0 = blockIdx.x * 32, r0 = blockIdx.y * 32;
  int tx = threadIdx.x, ty = threadIdx.y;
  #pragma unroll
  for (int i = ty; i < 32; i += 8)
    tile[i][tx] = in[(size_t)(r0 + i) * C + (c0 + tx)];
  __syncthreads();
  #pragma unroll
  for (int i = ty; i < 32; i += 8)
    out[(size_t)(c0 + i) * R + (r0 + tx)] = f2bf(tile[tx][i]);
}

// ---------------------------------------------------------------- GEMM  C(M,N) = A(M,K) * Bt(N,K)^T
__global__ __launch_bounds__(256) void gemm_bt_kernel(const unsigned short* __restrict__ A,
                                                      const unsigned short* __restrict__ Bt,
                                                      float* __restrict__ C,
                                                      int M, int N, int K) {
  __shared__ __attribute__((aligned(16))) unsigned short As[128 * 64];
  __shared__ __attribute__((aligned(16))) unsigned short Bs[128 * 64];
  const int tid = threadIdx.x;
  const int wave = tid >> 6, lane = tid & 63;
  const int wr = wave >> 1, wc = wave & 1;               // 2x2 wave grid, 64x64 each
  const int m0 = blockIdx.y * 128, n0 = blockIdx.x * 128;

  f32x4 acc[4][4] = {};

  const int srow = lane >> 3;           // staging row within 1KB chunk (8 rows of 64 elems)
  const int scol = (lane & 7) * 8;      // staging col (elems)

  for (int k0 = 0; k0 < K; k0 += 64) {
    #pragma unroll
    for (int c = 0; c < 4; ++c) {
      int ci  = wave * 4 + c;           // 0..15 chunk of the 16KB tile
      int row = ci * 8 + srow;          // 0..127
      GLL16(A  + (size_t)(m0 + row) * K + k0 + scol, &As[ci * 512]);
      GLL16(Bt + (size_t)(n0 + row) * K + k0 + scol, &Bs[ci * 512]);
    }
    __syncthreads();
    #pragma unroll
    for (int kk = 0; kk < 2; ++kk) {
      bf16x8 a[4], b[4];
      #pragma unroll
      for (int i = 0; i < 4; ++i) {
        a[i] = *reinterpret_cast<const bf16x8*>(
            &As[(wr * 64 + i * 16 + (lane & 15)) * 64 + kk * 32 + (lane >> 4) * 8]);
        b[i] = *reinterpret_cast<const bf16x8*>(
            &Bs[(wc * 64 + i * 16 + (lane & 15)) * 64 + kk * 32 + (lane >> 4) * 8]);
      }
      #pragma unroll
      for (int i = 0; i < 4; ++i)
        #pragma unroll
        for (int j = 0; j < 4; ++j)
          acc[i][j] = __builtin_amdgcn_mfma_f32_16x16x32_bf16(a[i], b[j], acc[i][j], 0, 0, 0);
    }
    __syncthreads();
  }

  #pragma unroll
  for (int i = 0; i < 4; ++i)
    #pragma unroll
    for (int j = 0; j < 4; ++j) {
      int col  = n0 + wc * 64 + j * 16 + (lane & 15);
      int rowb = m0 + wr * 64 + i * 16 + (lane >> 4) * 4;
      #pragma unroll
      for (int r = 0; r < 4; ++r)
        C[(size_t)(rowb + r) * N + col] = acc[i][j][r];
    }
}

// ---------------------------------------------------------------- bias + RoPE + relayout
// qlin: [L][H*D] fp32 -> qb: [H][L][D] bf16 (pre-scaled by QSCALE)
__global__ __launch_bounds__(128) void rope_q_kernel(const float* __restrict__ qlin,
                                                     const float* __restrict__ bq,
                                                     const float* __restrict__ cosT,
                                                     const float* __restrict__ sinT,
                                                     unsigned short* __restrict__ qb) {
  int l = blockIdx.x, h = blockIdx.y, d = threadIdx.x;
  size_t base = (size_t)l * (NH * DH) + h * DH;
  float v = qlin[base + d] + bq[h * DH + d];
  float o;
  if (d < 32) {
    float x2 = qlin[base + d + 32] + bq[h * DH + d + 32];
    o = v * cosT[l * 32 + d] - x2 * sinT[l * 32 + d];
  } else if (d < 64) {
    int i = d - 32;
    float x1 = qlin[base + i] + bq[h * DH + i];
    o = v * cosT[l * 32 + i] + x1 * sinT[l * 32 + i];
  } else {
    o = v;
  }
  qb[((size_t)h * L_SEQ + l) * DH + d] = f2bf(o * QSCALE);
}

// kvlin: [L][512] fp32 (cols 0..255 = K, 256..511 = V)
__global__ __launch_bounds__(128) void rope_k_kernel(const float* __restrict__ kvlin,
                                                     const float* __restrict__ bk,
                                                     const float* __restrict__ cosT,
                                                     const float* __restrict__ sinT,
                                                     unsigned short* __restrict__ kb) {
  int l = blockIdx.x, g = blockIdx.y, d = threadIdx.x;
  size_t base = (size_t)l * 512 + g * DH;
  float v = kvlin[base + d] + bk[g * DH + d];
  float o;
  if (d < 32) {
    float x2 = kvlin[base + d + 32] + bk[g * DH + d + 32];
    o = v * cosT[l * 32 + d] - x2 * sinT[l * 32 + d];
  } else if (d < 64) {
    int i = d - 32;
    float x1 = kvlin[base + i] + bk[g * DH + i];
    o = v * cosT[l * 32 + i] + x1 * sinT[l * 32 + i];
  } else {
    o = v;
  }
  kb[((size_t)g * L_SEQ + l) * DH + d] = f2bf(o);
}

// V stored transposed: vt[g][d][l]  (so PV B-fragments read contiguous along keys)
__global__ __launch_bounds__(128) void bias_vt_kernel(const float* __restrict__ kvlin,
                                                      const float* __restrict__ bv,
                                                      unsigned short* __restrict__ vt) {
  int l = blockIdx.x, g = blockIdx.y, d = threadIdx.x;
  float o = kvlin[(size_t)l * 512 + 256 + g * DH + d] + bv[g * DH + d];
  vt[((size_t)g * DH + d) * L_SEQ + l] = f2bf(o);
}

// ---------------------------------------------------------------- flash attention
// grid (L/64, H); 256 threads = 4 waves; wave w owns q-rows qt*64+w*16 .. +16
__global__ __launch_bounds__(256) void attn_kernel(const unsigned short* __restrict__ qb,
                                                   const unsigned short* __restrict__ kb,
                                                   const unsigned short* __restrict__ vt,
                                                   unsigned short* __restrict__ ob) {
  __shared__ __attribute__((aligned(16))) unsigned short Ks[32 * 128];   // [key][d]
  __shared__ __attribute__((aligned(16))) unsigned short Vs[128 * 32];   // [d][key]
  __shared__ __attribute__((aligned(16))) unsigned short Ps[4][16 * 32]; // per-wave P tile

  const int qt = blockIdx.x, h = blockIdx.y;
  const int g = h >> 4;                        // GQA: 16 q-heads per kv-head
  const int tid = threadIdx.x, wave = tid >> 6, lane = tid & 63;
  const int q0 = qt * 64 + wave * 16;

  bf16x8 qf[4];
  const unsigned short* qrow =
      qb + ((size_t)h * L_SEQ + q0 + (lane & 15)) * DH + (lane >> 4) * 8;
  #pragma unroll
  for (int f = 0; f < 4; ++f)
    qf[f] = *reinterpret_cast<const bf16x8*>(qrow + f * 32);

  f32x4 of[8] = {};
  float mrow[4] = {-1e30f, -1e30f, -1e30f, -1e30f};
  float lrow[4] = {0.f, 0.f, 0.f, 0.f};

  const int kv_end = qt * 64 + 64;
  for (int kv0 = 0; kv0 < kv_end; kv0 += 32) {
    #pragma unroll
    for (int c = 0; c < 2; ++c) {
      int ci = wave * 2 + c;                                   // 0..7
      {
        int key = ci * 4 + (lane >> 4);
        int d   = (lane & 15) * 8;
        GLL16(kb + ((size_t)g * L_SEQ + kv0 + key) * DH + d, &Ks[ci * 512]);
      }
      {
        int d   = ci * 16 + (lane >> 2);
        int key = (lane & 3) * 8;
        GLL16(vt + ((size_t)g * DH + d) * L_SEQ + kv0 + key, &Vs[ci * 512]);
      }
    }
    __syncthreads();

    if (kv0 <= q0 + 15) {                 // wave-uniform: skip tiles fully past diagonal
      f32x4 s0 = {}, s1 = {};
      #pragma unroll
      for (int f = 0; f < 4; ++f) {
        bf16x8 k0f = *reinterpret_cast<const bf16x8*>(
            &Ks[(lane & 15) * 128 + f * 32 + (lane >> 4) * 8]);
        bf16x8 k1f = *reinterpret_cast<const bf16x8*>(
            &Ks[(16 + (lane & 15)) * 128 + f * 32 + (lane >> 4) * 8]);
        s0 = __builtin_amdgcn_mfma_f32_16x16x32_bf16(qf[f], k0f, s0, 0, 0, 0);
        s1 = __builtin_amdgcn_mfma_f32_16x16x32_bf16(qf[f], k1f, s1, 0, 0, 0);
      }
      const int rowb = q0 + (lane >> 4) * 4;
      const int colb = kv0 + (lane & 15);
      if (kv0 + 31 > q0) {                // diagonal tile: apply causal mask
        #pragma unroll
        for (int r = 0; r < 4; ++r) {
          if (colb > rowb + r)      s0[r] = -1e30f;
          if (colb + 16 > rowb + r) s1[r] = -1e30f;
        }
      }
      float alpha[4];
      #pragma unroll
      for (int r = 0; r < 4; ++r) {
        float mx = fmaxf(s0[r], s1[r]);
        #pragma unroll
        for (int msk = 1; msk < 16; msk <<= 1) mx = fmaxf(mx, __shfl_xor(mx, msk));
        float mnew = fmaxf(mrow[r], mx);
        alpha[r] = __expf(mrow[r] - mnew);
        mrow[r] = mnew;
        float p0 = __expf(s0[r] - mnew);
        float p1 = __expf(s1[r] - mnew);
        s0[r] = p0; s1[r] = p1;
        float sum = p0 + p1;
        #pragma unroll
        for (int msk = 1; msk < 16; msk <<= 1) sum += __shfl_xor(sum, msk);
        lrow[r] = lrow[r] * alpha[r] + sum;
      }
      #pragma unroll
      for (int sl = 0; sl < 8; ++sl)
        #pragma unroll
        for (int r = 0; r < 4; ++r)
          of[sl][r] *= alpha[r];

      // P (C-layout) -> LDS -> A-fragment layout, same wave, no barrier needed
      unsigned short* pw = &Ps[wave][0];
      #pragma unroll
      for (int r = 0; r < 4; ++r) {
        int rr = (lane >> 4) * 4 + r;
        pw[rr * 32 + (lane & 15)]      = f2bf(s0[r]);
        pw[rr * 32 + 16 + (lane & 15)] = f2bf(s1[r]);
      }
      bf16x8 pa = *reinterpret_cast<const bf16x8*>(&pw[(lane & 15) * 32 + (lane >> 4) * 8]);
      #pragma unroll
      for (int sl = 0; sl < 8; ++sl) {
        bf16x8 vf = *reinterpret_cast<const bf16x8*>(
            &Vs[(sl * 16 + (lane & 15)) * 32 + (lane >> 4) * 8]);
        of[sl] = __builtin_amdgcn_mfma_f32_16x16x32_bf16(pa, vf, of[sl], 0, 0, 0);
      }
    }
    __syncthreads();
  }

  float inv[4];
  #pragma unroll
  for (int r = 0; r < 4; ++r) inv[r] = 1.f / lrow[r];
  #pragma unroll
  for (int sl = 0; sl < 8; ++sl)
    #pragma unroll
    for (int r = 0; r < 4; ++r) {
      int row = q0 + (lane >> 4) * 4 + r;
      ob[(size_t)row * (NH * DH) + h * DH + sl * 16 + (lane & 15)] = f2bf(of[sl][r] * inv[r]);
    }
}

// ---------------------------------------------------------------- launch
extern "C" void kernel_launch(void* const* d_in, const int* in_sizes, int n_in,
                              void* d_out, int out_size, void* d_ws, size_t ws_size,
                              hipStream_t stream) {
  (void)in_sizes; (void)n_in; (void)out_size; (void)ws_size;
  const float* x    = (const float*)d_in[0];
  const float* Wq   = (const float*)d_in[1];
  const float* bq   = (const float*)d_in[2];
  const float* Wk   = (const float*)d_in[3];
  const float* bk   = (const float*)d_in[4];
  const float* Wv   = (const float*)d_in[5];
  const float* bv   = (const float*)d_in[6];
  const float* Wo   = (const float*)d_in[7];
  const float* cosT = (const float*)d_in[8];
  const float* sinT = (const float*)d_in[9];
  // d_in[10] = attention_mask: unused (causal mask computed arithmetically)

  char* ws = (char*)d_ws;
  size_t off = 0;
  auto alloc = [&](size_t bytes) { void* p = ws + off; off += (bytes + 255) & ~(size_t)255; return p; };
  unsigned short* xb    = (unsigned short*)alloc((size_t)L_SEQ * HID * 2);       // x bf16
  unsigned short* Wqt   = (unsigned short*)alloc((size_t)HID * HID * 2);         // Wq^T
  unsigned short* Wkvt  = (unsigned short*)alloc((size_t)512 * HID * 2);         // [Wk^T; Wv^T]
  unsigned short* Wot   = (unsigned short*)alloc((size_t)HID * HID * 2);         // Wo^T
  float*          qlin  = (float*)alloc((size_t)L_SEQ * HID * 4);                // q pre-rope
  float*          kvlin = (float*)alloc((size_t)L_SEQ * 512 * 4);                // k|v pre-rope
  unsigned short* qbuf  = (unsigned short*)alloc((size_t)NH * L_SEQ * DH * 2);   // [H][L][D]
  unsigned short* kbuf  = (unsigned short*)alloc((size_t)NKV * L_SEQ * DH * 2);  // [KV][L][D]
  unsigned short* vtb   = (unsigned short*)alloc((size_t)NKV * DH * L_SEQ * 2);  // [KV][D][L]
  unsigned short* attno = (unsigned short*)qlin;  // alias: qlin dead after rope_q

  cast_bf16_kernel<<<(L_SEQ * HID / 4 + 255) / 256, 256, 0, stream>>>(x, xb, L_SEQ * HID / 4);
  transpose_cast_kernel<<<dim3(HID / 32, HID / 32), dim3(32, 8), 0, stream>>>(Wq, Wqt, HID, HID);
  transpose_cast_kernel<<<dim3(256 / 32, HID / 32), dim3(32, 8), 0, stream>>>(Wk, Wkvt, HID, 256);
  transpose_cast_kernel<<<dim3(256 / 32, HID / 32), dim3(32, 8), 0, stream>>>(Wv, Wkvt + (size_t)256 * HID, HID, 256);
  transpose_cast_kernel<<<dim3(HID / 32, HID / 32), dim3(32, 8), 0, stream>>>(Wo, Wot, HID, HID);

  gemm_bt_kernel<<<dim3(HID / 128, L_SEQ / 128), 256, 0, stream>>>(xb, Wqt, qlin, L_SEQ, HID, HID);
  gemm_bt_kernel<<<dim3(512 / 128, L_SEQ / 128), 256, 0, stream>>>(xb, Wkvt, kvlin, L_SEQ, 512, HID);

  rope_q_kernel<<<dim3(L_SEQ, NH), 128, 0, stream>>>(qlin, bq, cosT, sinT, qbuf);
  rope_k_kernel<<<dim3(L_SEQ, NKV), 128, 0, stream>>>(kvlin, bk, cosT, sinT, kbuf);
  bias_vt_kernel<<<dim3(L_SEQ, NKV), 128, 0, stream>>>(kvlin, bv, vtb);

  attn_kernel<<<dim3(L_SEQ / 64, NH), 256, 0, stream>>>(qbuf, kbuf, vtb, attno);

  gemm_bt_kernel<<<dim3(HID / 128, L_SEQ / 128), 256, 0, stream>>>(attno, Wot, (float*)d_out, L_SEQ, HID, HID);
}

// Round 2
// 609.003 us; speedup vs baseline: 1.1075x; 1.1075x over previous
//
// GLM4 attention block (B=1, L=2048, HID=4096, H=32, KV=2, D=128, ROT=64) on MI355X.
// Round 2: attn rewritten — 4 waves x 32 q-rows (interleaved +0/+64), KVB=64,
//   XOR-swizzled K/V staging (pre-swizzled global source, linear LDS dest),
//   conflict-free fragment reads, rotated P buffer. XCD-chunked swizzle on GEMMs.
#include <hip/hip_runtime.h>
#include <stdint.h>

#define L_SEQ 2048
#define HID   4096
#define NH    32
#define NKV   2
#define DH    128
#define QSCALE 0.088388347648318447f   // 128^-0.5

typedef __bf16 bf16x8 __attribute__((ext_vector_type(8)));
typedef float  f32x4  __attribute__((ext_vector_type(4)));

__device__ __forceinline__ unsigned short f2bf(float f) {
  union { float f; unsigned u; } cv; cv.f = f;
  unsigned u = cv.u;
  return (unsigned short)((u + 0x7fffu + ((u >> 16) & 1u)) >> 16);   // RNE, finite-only
}

// async global->LDS, 16B per lane; LDS dest = wave-uniform base + lane*16
#define GLL16(gsrc, ldst)                                                              \
  __builtin_amdgcn_global_load_lds(                                                    \
      (const __attribute__((address_space(1))) unsigned int*)(gsrc),                   \
      (__attribute__((address_space(3))) unsigned int*)(ldst), 16, 0, 0)

// ---------------------------------------------------------------- casts
__global__ __launch_bounds__(256) void cast_bf16_kernel(const float* __restrict__ in,
                                                        unsigned short* __restrict__ out,
                                                        int n4) {
  int i = blockIdx.x * 256 + threadIdx.x;
  if (i >= n4) return;
  float4 v = reinterpret_cast<const float4*>(in)[i];
  ushort4 o;
  o.x = f2bf(v.x); o.y = f2bf(v.y); o.z = f2bf(v.z); o.w = f2bf(v.w);
  reinterpret_cast<ushort4*>(out)[i] = o;
}

// in: (R,C) fp32 row-major -> out: (C,R) bf16 row-major
__global__ __launch_bounds__(256) void transpose_cast_kernel(const float* __restrict__ in,
                                                             unsigned short* __restrict__ out,
                                                             int R, int C) {
  __shared__ float tile[32][33];
  int c0 = blockIdx.x * 32, r0 = blockIdx.y * 32;
  int tx = threadIdx.x, ty = threadIdx.y;
  #pragma unroll
  for (int i = ty; i < 32; i += 8)
    tile[i][tx] = in[(size_t)(r0 + i) * C + (c0 + tx)];
  __syncthreads();
  #pragma unroll
  for (int i = ty; i < 32; i += 8)
    out[(size_t)(c0 + i) * R + (r0 + tx)] = f2bf(tile[tx][i]);
}

// ---------------------------------------------------------------- GEMM  C(M,N) = A(M,K) * Bt(N,K)^T
__global__ __launch_bounds__(256) void gemm_bt_kernel(const unsigned short* __restrict__ A,
                                                      const unsigned short* __restrict__ Bt,
                                                      float* __restrict__ C,
                                                      int M, int N, int K) {
  __shared__ __attribute__((aligned(16))) unsigned short As[128 * 64];
  __shared__ __attribute__((aligned(16))) unsigned short Bs[128 * 64];
  const int tid = threadIdx.x;
  const int wave = tid >> 6, lane = tid & 63;
  const int wr = wave >> 1, wc = wave & 1;               // 2x2 wave grid, 64x64 each

  // XCD-chunked block swizzle (bijective when nwg%8==0): each XCD gets a
  // contiguous chunk of tile space -> A-panel reuse in its private L2.
  int gx = gridDim.x, nwg = gx * gridDim.y;
  int flat = blockIdx.y * gx + blockIdx.x;
  int bx = blockIdx.x, by = blockIdx.y;
  if ((nwg & 7) == 0) {
    int t = (flat & 7) * (nwg >> 3) + (flat >> 3);
    bx = t % gx; by = t / gx;
  }
  const int m0 = by * 128, n0 = bx * 128;

  f32x4 acc[4][4] = {};

  const int srow = lane >> 3;           // staging row within 1KB chunk (8 rows of 64 elems)
  const int scol = (lane & 7) * 8;      // staging col (elems)

  for (int k0 = 0; k0 < K; k0 += 64) {
    #pragma unroll
    for (int c = 0; c < 4; ++c) {
      int ci  = wave * 4 + c;           // 0..15 chunk of the 16KB tile
      int row = ci * 8 + srow;          // 0..127
      GLL16(A  + (size_t)(m0 + row) * K + k0 + scol, &As[ci * 512]);
      GLL16(Bt + (size_t)(n0 + row) * K + k0 + scol, &Bs[ci * 512]);
    }
    __syncthreads();
    #pragma unroll
    for (int kk = 0; kk < 2; ++kk) {
      bf16x8 a[4], b[4];
      #pragma unroll
      for (int i = 0; i < 4; ++i) {
        a[i] = *reinterpret_cast<const bf16x8*>(
            &As[(wr * 64 + i * 16 + (lane & 15)) * 64 + kk * 32 + (lane >> 4) * 8]);
        b[i] = *reinterpret_cast<const bf16x8*>(
            &Bs[(wc * 64 + i * 16 + (lane & 15)) * 64 + kk * 32 + (lane >> 4) * 8]);
      }
      #pragma unroll
      for (int i = 0; i < 4; ++i)
        #pragma unroll
        for (int j = 0; j < 4; ++j)
          acc[i][j] = __builtin_amdgcn_mfma_f32_16x16x32_bf16(a[i], b[j], acc[i][j], 0, 0, 0);
    }
    __syncthreads();
  }

  #pragma unroll
  for (int i = 0; i < 4; ++i)
    #pragma unroll
    for (int j = 0; j < 4; ++j) {
      int col  = n0 + wc * 64 + j * 16 + (lane & 15);
      int rowb = m0 + wr * 64 + i * 16 + (lane >> 4) * 4;
      #pragma unroll
      for (int r = 0; r < 4; ++r)
        C[(size_t)(rowb + r) * N + col] = acc[i][j][r];
    }
}

// ---------------------------------------------------------------- bias + RoPE + relayout
// qlin: [L][H*D] fp32 -> qb: [H][L][D] bf16 (pre-scaled by QSCALE)
__global__ __launch_bounds__(128) void rope_q_kernel(const float* __restrict__ qlin,
                                                     const float* __restrict__ bq,
                                                     const float* __restrict__ cosT,
                                                     const float* __restrict__ sinT,
                                                     unsigned short* __restrict__ qb) {
  int l = blockIdx.x, h = blockIdx.y, d = threadIdx.x;
  size_t base = (size_t)l * (NH * DH) + h * DH;
  float v = qlin[base + d] + bq[h * DH + d];
  float o;
  if (d < 32) {
    float x2 = qlin[base + d + 32] + bq[h * DH + d + 32];
    o = v * cosT[l * 32 + d] - x2 * sinT[l * 32 + d];
  } else if (d < 64) {
    int i = d - 32;
    float x1 = qlin[base + i] + bq[h * DH + i];
    o = v * cosT[l * 32 + i] + x1 * sinT[l * 32 + i];
  } else {
    o = v;
  }
  qb[((size_t)h * L_SEQ + l) * DH + d] = f2bf(o * QSCALE);
}

// kvlin: [L][512] fp32 (cols 0..255 = K, 256..511 = V)
__global__ __launch_bounds__(128) void rope_k_kernel(const float* __restrict__ kvlin,
                                                     const float* __restrict__ bk,
                                                     const float* __restrict__ cosT,
                                                     const float* __restrict__ sinT,
                                                     unsigned short* __restrict__ kb) {
  int l = blockIdx.x, g = blockIdx.y, d = threadIdx.x;
  size_t base = (size_t)l * 512 + g * DH;
  float v = kvlin[base + d] + bk[g * DH + d];
  float o;
  if (d < 32) {
    float x2 = kvlin[base + d + 32] + bk[g * DH + d + 32];
    o = v * cosT[l * 32 + d] - x2 * sinT[l * 32 + d];
  } else if (d < 64) {
    int i = d - 32;
    float x1 = kvlin[base + i] + bk[g * DH + i];
    o = v * cosT[l * 32 + i] + x1 * sinT[l * 32 + i];
  } else {
    o = v;
  }
  kb[((size_t)g * L_SEQ + l) * DH + d] = f2bf(o);
}

// V stored transposed: vt[g][d][l]  (so PV B-fragments read contiguous along keys)
__global__ __launch_bounds__(128) void bias_vt_kernel(const float* __restrict__ kvlin,
                                                      const float* __restrict__ bv,
                                                      unsigned short* __restrict__ vt) {
  int l = blockIdx.x, g = blockIdx.y, d = threadIdx.x;
  float o = kvlin[(size_t)l * 512 + 256 + g * DH + d] + bv[g * DH + d];
  vt[((size_t)g * DH + d) * L_SEQ + l] = f2bf(o);
}

// ---------------------------------------------------------------- flash attention
// grid (L/128, H); 256 threads = 4 waves.
// Wave w owns 32 q-rows: [qt*128 + w*16, +16) and [qt*128 + 64 + w*16, +16)
// (interleaved so every wave is active on every KV tile).
// K LDS [64][128] and V^T LDS [128][64], both chunk-XOR-swizzled:
//   physical 16B-chunk c' holds global chunk c' ^ (row & 7).
// P buffer per wave/rf: 16 rows x 72 elems, chunk rotated by (row + row>>2).
__device__ __forceinline__ int p_addr(int row, int chunk) {
  return row * 72 + (((chunk + row + (row >> 2)) & 7) * 8);
}

__global__ __launch_bounds__(256) void attn_kernel(const unsigned short* __restrict__ qg,
                                                   const unsigned short* __restrict__ kb,
                                                   const unsigned short* __restrict__ vt,
                                                   unsigned short* __restrict__ ob) {
  __shared__ __attribute__((aligned(16))) unsigned short Ks[64 * 128];
  __shared__ __attribute__((aligned(16))) unsigned short Vs[128 * 64];
  __shared__ __attribute__((aligned(16))) unsigned short Ps[4][2][16 * 72];

  const int qt = blockIdx.x, h = blockIdx.y;
  const int g = h >> 4;                         // 16 q-heads per kv-head
  const int tid = threadIdx.x, wave = tid >> 6, lane = tid & 63;
  const int lg = lane >> 4, ll = lane & 15;     // 16-lane group id, lane-in-group
  const int q_base = qt * 128 + wave * 16;      // rf0 base; rf1 = +64

  bf16x8 qf[2][4];
  #pragma unroll
  for (int rf = 0; rf < 2; ++rf)
    #pragma unroll
    for (int f = 0; f < 4; ++f)
      qf[rf][f] = *reinterpret_cast<const bf16x8*>(
          qg + ((size_t)h * L_SEQ + q_base + rf * 64 + ll) * DH + f * 32 + lg * 8);

  f32x4 of[2][8] = {};
  float mrow[2][4], lrow[2][4];
  #pragma unroll
  for (int rf = 0; rf < 2; ++rf)
    #pragma unroll
    for (int r = 0; r < 4; ++r) { mrow[rf][r] = -1e30f; lrow[rf][r] = 0.f; }

  const int kv_end = qt * 128 + 128;
  for (int kv0 = 0; kv0 < kv_end; kv0 += 64) {
    // ---- stage K (16KB) + V^T (16KB), pre-swizzled global source
    #pragma unroll
    for (int c = 0; c < 4; ++c) {
      int issue = wave * 4 + c;
      {
        int rowl = issue * 4 + (lane >> 4);            // 0..63 key row
        int cg   = (lane & 15) ^ (rowl & 7);           // global 16B chunk
        GLL16(kb + ((size_t)g * L_SEQ + kv0 + rowl) * DH + cg * 8, &Ks[issue * 512]);
      }
      {
        int dl = issue * 8 + (lane >> 3);              // 0..127 d row
        int cg = (lane & 7) ^ (dl & 7);
        GLL16(vt + ((size_t)g * DH + dl) * L_SEQ + kv0 + cg * 8, &Vs[issue * 512]);
      }
    }
    __syncthreads();

    const bool act0 = (kv0 <= q_base + 15);
    f32x4 s[2][4] = {};
    #pragma unroll
    for (int cf = 0; cf < 4; ++cf) {
      bf16x8 kf[4];
      #pragma unroll
      for (int f = 0; f < 4; ++f) {
        int rk = cf * 16 + ll;
        int cc = (f * 4 + lg) ^ (rk & 7);
        kf[f] = *reinterpret_cast<const bf16x8*>(&Ks[rk * 128 + cc * 8]);
      }
      #pragma unroll
      for (int f = 0; f < 4; ++f)
        s[1][cf] = __builtin_amdgcn_mfma_f32_16x16x32_bf16(qf[1][f], kf[f], s[1][cf], 0, 0, 0);
      if (act0) {
        #pragma unroll
        for (int f = 0; f < 4; ++f)
          s[0][cf] = __builtin_amdgcn_mfma_f32_16x16x32_bf16(qf[0][f], kf[f], s[0][cf], 0, 0, 0);
      }
    }

    #pragma unroll
    for (int rf = 0; rf < 2; ++rf) {
      if (rf == 0 && !act0) continue;
      const int qb = q_base + rf * 64;
      if (kv0 + 63 > qb) {                               // diagonal: causal mask
        #pragma unroll
        for (int cf = 0; cf < 4; ++cf)
          #pragma unroll
          for (int r = 0; r < 4; ++r)
            if (kv0 + cf * 16 + ll > qb + lg * 4 + r) s[rf][cf][r] = -1e30f;
      }
      float alpha[4];
      #pragma unroll
      for (int r = 0; r < 4; ++r) {
        float mx = fmaxf(fmaxf(s[rf][0][r], s[rf][1][r]), fmaxf(s[rf][2][r], s[rf][3][r]));
        #pragma unroll
        for (int msk = 1; msk < 16; msk <<= 1) mx = fmaxf(mx, __shfl_xor(mx, msk));
        float mnew = fmaxf(mrow[rf][r], mx);
        alpha[r] = __expf(mrow[rf][r] - mnew);
        mrow[rf][r] = mnew;
        float sum = 0.f;
        #pragma unroll
        for (int cf = 0; cf < 4; ++cf) {
          s[rf][cf][r] = __expf(s[rf][cf][r] - mnew);
          sum += s[rf][cf][r];
        }
        #pragma unroll
        for (int msk = 1; msk < 16; msk <<= 1) sum += __shfl_xor(sum, msk);
        lrow[rf][r] = lrow[rf][r] * alpha[r] + sum;
      }
      #pragma unroll
      for (int ds = 0; ds < 8; ++ds)
        #pragma unroll
        for (int r = 0; r < 4; ++r)
          of[rf][ds][r] *= alpha[r];

      // P (C-layout) -> per-wave LDS (rotated chunks) -> A-fragments
      unsigned short* pw = &Ps[wave][rf][0];
      #pragma unroll
      for (int cf = 0; cf < 4; ++cf)
        #pragma unroll
        for (int r = 0; r < 4; ++r) {
          int rr = lg * 4 + r;
          int c  = cf * 16 + ll;
          pw[p_addr(rr, c >> 3) + (c & 7)] = f2bf(s[rf][cf][r]);
        }
      bf16x8 pa[2];
      #pragma unroll
      for (int ks = 0; ks < 2; ++ks)
        pa[ks] = *reinterpret_cast<const bf16x8*>(&pw[p_addr(ll, ks * 4 + lg)]);
      #pragma unroll
      for (int ds = 0; ds < 8; ++ds) {
        #pragma unroll
        for (int ks = 0; ks < 2; ++ks) {
          int dl = ds * 16 + ll;
          int cc = (ks * 4 + lg) ^ (dl & 7);
          bf16x8 vf = *reinterpret_cast<const bf16x8*>(&Vs[dl * 64 + cc * 8]);
          of[rf][ds] = __builtin_amdgcn_mfma_f32_16x16x32_bf16(pa[ks], vf, of[rf][ds], 0, 0, 0);
        }
      }
    }
    __syncthreads();
  }

  #pragma unroll
  for (int rf = 0; rf < 2; ++rf) {
    float inv[4];
    #pragma unroll
    for (int r = 0; r < 4; ++r) inv[r] = 1.f / lrow[rf][r];
    #pragma unroll
    for (int ds = 0; ds < 8; ++ds)
      #pragma unroll
      for (int r = 0; r < 4; ++r) {
        int row = q_base + rf * 64 + lg * 4 + r;
        ob[(size_t)row * (NH * DH) + h * DH + ds * 16 + ll] = f2bf(of[rf][ds][r] * inv[r]);
      }
  }
}

// ---------------------------------------------------------------- launch
extern "C" void kernel_launch(void* const* d_in, const int* in_sizes, int n_in,
                              void* d_out, int out_size, void* d_ws, size_t ws_size,
                              hipStream_t stream) {
  (void)in_sizes; (void)n_in; (void)out_size; (void)ws_size;
  const float* x    = (const float*)d_in[0];
  const float* Wq   = (const float*)d_in[1];
  const float* bq   = (const float*)d_in[2];
  const float* Wk   = (const float*)d_in[3];
  const float* bk   = (const float*)d_in[4];
  const float* Wv   = (const float*)d_in[5];
  const float* bv   = (const float*)d_in[6];
  const float* Wo   = (const float*)d_in[7];
  const float* cosT = (const float*)d_in[8];
  const float* sinT = (const float*)d_in[9];
  // d_in[10] = attention_mask: unused (causal mask computed arithmetically)

  char* ws = (char*)d_ws;
  size_t off = 0;
  auto alloc = [&](size_t bytes) { void* p = ws + off; off += (bytes + 255) & ~(size_t)255; return p; };
  unsigned short* xb    = (unsigned short*)alloc((size_t)L_SEQ * HID * 2);       // x bf16
  unsigned short* Wqt   = (unsigned short*)alloc((size_t)HID * HID * 2);         // Wq^T
  unsigned short* Wkvt  = (unsigned short*)alloc((size_t)512 * HID * 2);         // [Wk^T; Wv^T]
  unsigned short* Wot   = (unsigned short*)alloc((size_t)HID * HID * 2);         // Wo^T
  float*          qlin  = (float*)alloc((size_t)L_SEQ * HID * 4);                // q pre-rope
  float*          kvlin = (float*)alloc((size_t)L_SEQ * 512 * 4);                // k|v pre-rope
  unsigned short* qbuf  = (unsigned short*)alloc((size_t)NH * L_SEQ * DH * 2);   // [H][L][D]
  unsigned short* kbuf  = (unsigned short*)alloc((size_t)NKV * L_SEQ * DH * 2);  // [KV][L][D]
  unsigned short* vtb   = (unsigned short*)alloc((size_t)NKV * DH * L_SEQ * 2);  // [KV][D][L]
  unsigned short* attno = (unsigned short*)qlin;  // alias: qlin dead after rope_q

  cast_bf16_kernel<<<(L_SEQ * HID / 4 + 255) / 256, 256, 0, stream>>>(x, xb, L_SEQ * HID / 4);
  transpose_cast_kernel<<<dim3(HID / 32, HID / 32), dim3(32, 8), 0, stream>>>(Wq, Wqt, HID, HID);
  transpose_cast_kernel<<<dim3(256 / 32, HID / 32), dim3(32, 8), 0, stream>>>(Wk, Wkvt, HID, 256);
  transpose_cast_kernel<<<dim3(256 / 32, HID / 32), dim3(32, 8), 0, stream>>>(Wv, Wkvt + (size_t)256 * HID, HID, 256);
  transpose_cast_kernel<<<dim3(HID / 32, HID / 32), dim3(32, 8), 0, stream>>>(Wo, Wot, HID, HID);

  gemm_bt_kernel<<<dim3(HID / 128, L_SEQ / 128), 256, 0, stream>>>(xb, Wqt, qlin, L_SEQ, HID, HID);
  gemm_bt_kernel<<<dim3(512 / 128, L_SEQ / 128), 256, 0, stream>>>(xb, Wkvt, kvlin, L_SEQ, 512, HID);

  rope_q_kernel<<<dim3(L_SEQ, NH), 128, 0, stream>>>(qlin, bq, cosT, sinT, qbuf);
  rope_k_kernel<<<dim3(L_SEQ, NKV), 128, 0, stream>>>(kvlin, bk, cosT, sinT, kbuf);
  bias_vt_kernel<<<dim3(L_SEQ, NKV), 128, 0, stream>>>(kvlin, bv, vtb);

  attn_kernel<<<dim3(L_SEQ / 128, NH), 256, 0, stream>>>(qbuf, kbuf, vtb, attno);

  gemm_bt_kernel<<<dim3(HID / 128, L_SEQ / 128), 256, 0, stream>>>(attno, Wot, (float*)d_out, L_SEQ, HID, HID);
}

// Round 3
// 452.207 us; speedup vs baseline: 1.4915x; 1.3467x over previous
//
// GLM4 attention block (B=1, L=2048, HID=4096, H=32, KV=2, D=128, ROT=64) on MI355X.
// Round 3: attn load-balanced (causal fold-pairing, QB=64, uniform 33 tiles/block),
//   double-buffered K/V staging (stage-early 2-phase), defer-max softmax (T13),
//   per-lane partial l-sum (epilogue reduce), setprio (T5).
//   QKV projections fused into one N=4608 GEMM. XCD-chunked swizzle on GEMMs.
#include <hip/hip_runtime.h>
#include <stdint.h>

#define L_SEQ 2048
#define HID   4096
#define NH    32
#define NKV   2
#define DH    128
#define NQKV  4608                     // H*D + 2*KV*D
#define QSCALE 0.088388347648318447f   // 128^-0.5

typedef __bf16 bf16x8 __attribute__((ext_vector_type(8)));
typedef float  f32x4  __attribute__((ext_vector_type(4)));

__device__ __forceinline__ unsigned short f2bf(float f) {
  union { float f; unsigned u; } cv; cv.f = f;
  unsigned u = cv.u;
  return (unsigned short)((u + 0x7fffu + ((u >> 16) & 1u)) >> 16);   // RNE, finite-only
}

// async global->LDS, 16B per lane; LDS dest = wave-uniform base + lane*16
#define GLL16(gsrc, ldst)                                                              \
  __builtin_amdgcn_global_load_lds(                                                    \
      (const __attribute__((address_space(1))) unsigned int*)(gsrc),                   \
      (__attribute__((address_space(3))) unsigned int*)(ldst), 16, 0, 0)

// ---------------------------------------------------------------- casts
__global__ __launch_bounds__(256) void cast_bf16_kernel(const float* __restrict__ in,
                                                        unsigned short* __restrict__ out,
                                                        int n4) {
  int i = blockIdx.x * 256 + threadIdx.x;
  if (i >= n4) return;
  float4 v = reinterpret_cast<const float4*>(in)[i];
  ushort4 o;
  o.x = f2bf(v.x); o.y = f2bf(v.y); o.z = f2bf(v.z); o.w = f2bf(v.w);
  reinterpret_cast<ushort4*>(out)[i] = o;
}

// in: (R,C) fp32 row-major -> out: (C,R) bf16 row-major
__global__ __launch_bounds__(256) void transpose_cast_kernel(const float* __restrict__ in,
                                                             unsigned short* __restrict__ out,
                                                             int R, int C) {
  __shared__ float tile[32][33];
  int c0 = blockIdx.x * 32, r0 = blockIdx.y * 32;
  int tx = threadIdx.x, ty = threadIdx.y;
  #pragma unroll
  for (int i = ty; i < 32; i += 8)
    tile[i][tx] = in[(size_t)(r0 + i) * C + (c0 + tx)];
  __syncthreads();
  #pragma unroll
  for (int i = ty; i < 32; i += 8)
    out[(size_t)(c0 + i) * R + (r0 + tx)] = f2bf(tile[tx][i]);
}

// ---------------------------------------------------------------- GEMM  C(M,N) = A(M,K) * Bt(N,K)^T
__global__ __launch_bounds__(256) void gemm_bt_kernel(const unsigned short* __restrict__ A,
                                                      const unsigned short* __restrict__ Bt,
                                                      float* __restrict__ C,
                                                      int M, int N, int K) {
  __shared__ __attribute__((aligned(16))) unsigned short As[128 * 64];
  __shared__ __attribute__((aligned(16))) unsigned short Bs[128 * 64];
  const int tid = threadIdx.x;
  const int wave = tid >> 6, lane = tid & 63;
  const int wr = wave >> 1, wc = wave & 1;               // 2x2 wave grid, 64x64 each

  // XCD-chunked block swizzle (bijective when nwg%8==0)
  int gx = gridDim.x, nwg = gx * gridDim.y;
  int flat = blockIdx.y * gx + blockIdx.x;
  int bx = blockIdx.x, by = blockIdx.y;
  if ((nwg & 7) == 0) {
    int t = (flat & 7) * (nwg >> 3) + (flat >> 3);
    bx = t % gx; by = t / gx;
  }
  const int m0 = by * 128, n0 = bx * 128;

  f32x4 acc[4][4] = {};

  const int srow = lane >> 3;
  const int scol = (lane & 7) * 8;

  for (int k0 = 0; k0 < K; k0 += 64) {
    #pragma unroll
    for (int c = 0; c < 4; ++c) {
      int ci  = wave * 4 + c;
      int row = ci * 8 + srow;
      GLL16(A  + (size_t)(m0 + row) * K + k0 + scol, &As[ci * 512]);
      GLL16(Bt + (size_t)(n0 + row) * K + k0 + scol, &Bs[ci * 512]);
    }
    __syncthreads();
    #pragma unroll
    for (int kk = 0; kk < 2; ++kk) {
      bf16x8 a[4], b[4];
      #pragma unroll
      for (int i = 0; i < 4; ++i) {
        a[i] = *reinterpret_cast<const bf16x8*>(
            &As[(wr * 64 + i * 16 + (lane & 15)) * 64 + kk * 32 + (lane >> 4) * 8]);
        b[i] = *reinterpret_cast<const bf16x8*>(
            &Bs[(wc * 64 + i * 16 + (lane & 15)) * 64 + kk * 32 + (lane >> 4) * 8]);
      }
      #pragma unroll
      for (int i = 0; i < 4; ++i)
        #pragma unroll
        for (int j = 0; j < 4; ++j)
          acc[i][j] = __builtin_amdgcn_mfma_f32_16x16x32_bf16(a[i], b[j], acc[i][j], 0, 0, 0);
    }
    __syncthreads();
  }

  #pragma unroll
  for (int i = 0; i < 4; ++i)
    #pragma unroll
    for (int j = 0; j < 4; ++j) {
      int col  = n0 + wc * 64 + j * 16 + (lane & 15);
      int rowb = m0 + wr * 64 + i * 16 + (lane >> 4) * 4;
      #pragma unroll
      for (int r = 0; r < 4; ++r)
        C[(size_t)(rowb + r) * N + col] = acc[i][j][r];
    }
}

// ---------------------------------------------------------------- bias + RoPE + relayout
// qkv: [L][4608] fp32. cols 0..4095 = Q, 4096..4351 = K, 4352..4607 = V.
__global__ __launch_bounds__(128) void rope_q_kernel(const float* __restrict__ qkv,
                                                     const float* __restrict__ bq,
                                                     const float* __restrict__ cosT,
                                                     const float* __restrict__ sinT,
                                                     unsigned short* __restrict__ qb) {
  int l = blockIdx.x, h = blockIdx.y, d = threadIdx.x;
  size_t base = (size_t)l * NQKV + h * DH;
  float v = qkv[base + d] + bq[h * DH + d];
  float o;
  if (d < 32) {
    float x2 = qkv[base + d + 32] + bq[h * DH + d + 32];
    o = v * cosT[l * 32 + d] - x2 * sinT[l * 32 + d];
  } else if (d < 64) {
    int i = d - 32;
    float x1 = qkv[base + i] + bq[h * DH + i];
    o = v * cosT[l * 32 + i] + x1 * sinT[l * 32 + i];
  } else {
    o = v;
  }
  qb[((size_t)h * L_SEQ + l) * DH + d] = f2bf(o * QSCALE);
}

__global__ __launch_bounds__(128) void rope_k_kernel(const float* __restrict__ qkv,
                                                     const float* __restrict__ bk,
                                                     const float* __restrict__ cosT,
                                                     const float* __restrict__ sinT,
                                                     unsigned short* __restrict__ kb) {
  int l = blockIdx.x, g = blockIdx.y, d = threadIdx.x;
  size_t base = (size_t)l * NQKV + 4096 + g * DH;
  float v = qkv[base + d] + bk[g * DH + d];
  float o;
  if (d < 32) {
    float x2 = qkv[base + d + 32] + bk[g * DH + d + 32];
    o = v * cosT[l * 32 + d] - x2 * sinT[l * 32 + d];
  } else if (d < 64) {
    int i = d - 32;
    float x1 = qkv[base + i] + bk[g * DH + i];
    o = v * cosT[l * 32 + i] + x1 * sinT[l * 32 + i];
  } else {
    o = v;
  }
  kb[((size_t)g * L_SEQ + l) * DH + d] = f2bf(o);
}

// V stored transposed: vt[g][d][l]
__global__ __launch_bounds__(128) void bias_vt_kernel(const float* __restrict__ qkv,
                                                      const float* __restrict__ bv,
                                                      unsigned short* __restrict__ vt) {
  int l = blockIdx.x, g = blockIdx.y, d = threadIdx.x;
  float o = qkv[(size_t)l * NQKV + 4352 + g * DH + d] + bv[g * DH + d];
  vt[((size_t)g * DH + d) * L_SEQ + l] = f2bf(o);
}

// ---------------------------------------------------------------- flash attention
// grid (16, H); 256 threads = 4 waves. Causal fold-pairing: block pair p handles
// q-tiles p and 31-p (QB=64) sequentially -> uniform 33 KV-tiles per block.
// Wave w owns q-rows qt*64 + w*16 .. +16.
// K LDS [2][64][128], V^T LDS [2][128][64], chunk-XOR-swizzled, double-buffered:
// stage(next) issued before compute(cur); single barrier per tile.
__device__ __forceinline__ int p_addr(int row, int chunk) {
  return row * 72 + (((chunk + row + (row >> 2)) & 7) * 8);
}

__global__ __launch_bounds__(256) void attn_kernel(const unsigned short* __restrict__ qg,
                                                   const unsigned short* __restrict__ kb,
                                                   const unsigned short* __restrict__ vt,
                                                   unsigned short* __restrict__ ob) {
  __shared__ __attribute__((aligned(16))) unsigned short Ks[2][64 * 128];
  __shared__ __attribute__((aligned(16))) unsigned short Vs[2][128 * 64];
  __shared__ __attribute__((aligned(16))) unsigned short Ps[4][16 * 72];

  const int pair = blockIdx.x, h = blockIdx.y;
  const int g = h >> 4;                         // 16 q-heads per kv-head
  const int tid = threadIdx.x, wave = tid >> 6, lane = tid & 63;
  const int lg = lane >> 4, ll = lane & 15;

  // per-wave staging coords (constant across tiles)
  const int krow = (lane >> 4);                 // + issue*4
  const int kcg0 = (lane & 15);
  const int vrow = (lane >> 3);                 // + issue*8
  const int vcg0 = (lane & 7);

  #pragma unroll
  for (int seg = 0; seg < 2; ++seg) {
    const int qt = seg ? (31 - pair) : pair;
    const int q0 = qt * 64 + wave * 16;

    bf16x8 qf[4];
    #pragma unroll
    for (int f = 0; f < 4; ++f)
      qf[f] = *reinterpret_cast<const bf16x8*>(
          qg + ((size_t)h * L_SEQ + q0 + ll) * DH + f * 32 + lg * 8);

    f32x4 of[8] = {};
    float m[4]  = {-1e30f, -1e30f, -1e30f, -1e30f};
    float lsum[4] = {0.f, 0.f, 0.f, 0.f};       // per-lane partial row sums

    const int kvN = qt + 1;
    int cur = 0;

    // prologue stage tile 0 into buf 0
    #pragma unroll
    for (int c = 0; c < 4; ++c) {
      int issue = wave * 4 + c;
      int rk = issue * 4 + krow;
      GLL16(kb + ((size_t)g * L_SEQ + rk) * DH + (kcg0 ^ (rk & 7)) * 8, &Ks[0][issue * 512]);
      int rv = issue * 8 + vrow;
      GLL16(vt + ((size_t)g * DH + rv) * L_SEQ + (vcg0 ^ (rv & 7)) * 8, &Vs[0][issue * 512]);
    }
    __syncthreads();

    for (int t = 0; t < kvN; ++t) {
      // ---- prefetch next tile into the other buffer (latency hides under compute)
      if (t + 1 < kvN) {
        int kv1 = (t + 1) * 64;
        #pragma unroll
        for (int c = 0; c < 4; ++c) {
          int issue = wave * 4 + c;
          int rk = issue * 4 + krow;
          GLL16(kb + ((size_t)g * L_SEQ + kv1 + rk) * DH + (kcg0 ^ (rk & 7)) * 8,
                &Ks[cur ^ 1][issue * 512]);
          int rv = issue * 8 + vrow;
          GLL16(vt + ((size_t)g * DH + rv) * L_SEQ + kv1 + (vcg0 ^ (rv & 7)) * 8,
                &Vs[cur ^ 1][issue * 512]);
        }
      }

      // ---- QK^T
      f32x4 s[4] = {};
      const unsigned short* Kc = &Ks[cur][0];
      #pragma unroll
      for (int cf = 0; cf < 4; ++cf) {
        bf16x8 kf[4];
        #pragma unroll
        for (int f = 0; f < 4; ++f) {
          int rk = cf * 16 + ll;
          int cc = (f * 4 + lg) ^ (rk & 7);
          kf[f] = *reinterpret_cast<const bf16x8*>(&Kc[rk * 128 + cc * 8]);
        }
        __builtin_amdgcn_s_setprio(1);
        #pragma unroll
        for (int f = 0; f < 4; ++f)
          s[cf] = __builtin_amdgcn_mfma_f32_16x16x32_bf16(qf[f], kf[f], s[cf], 0, 0, 0);
        __builtin_amdgcn_s_setprio(0);
      }

      // ---- causal mask (diagonal tile only)
      if (t == qt) {
        #pragma unroll
        for (int cf = 0; cf < 4; ++cf)
          #pragma unroll
          for (int r = 0; r < 4; ++r)
            if (cf * 16 + ll > wave * 16 + lg * 4 + r) s[cf][r] = -1e30f;
      }

      // ---- defer-max online softmax (T13)
      float pmax[4];
      #pragma unroll
      for (int r = 0; r < 4; ++r)
        pmax[r] = fmaxf(fmaxf(s[0][r], s[1][r]), fmaxf(s[2][r], s[3][r]));
      bool ok = true;
      #pragma unroll
      for (int r = 0; r < 4; ++r) ok = ok && (pmax[r] - m[r] <= 8.f);
      if (!__all(ok)) {
        // full rescale path (rare): proper row max, rescale O and lsum
        float alpha[4];
        #pragma unroll
        for (int r = 0; r < 4; ++r) {
          float mx = pmax[r];
          #pragma unroll
          for (int msk = 1; msk < 16; msk <<= 1) mx = fmaxf(mx, __shfl_xor(mx, msk));
          float mnew = fmaxf(m[r], mx);
          alpha[r] = __expf(m[r] - mnew);
          m[r] = mnew;
          lsum[r] *= alpha[r];
        }
        #pragma unroll
        for (int ds = 0; ds < 8; ++ds)
          #pragma unroll
          for (int r = 0; r < 4; ++r)
            of[ds][r] *= alpha[r];
      }
      #pragma unroll
      for (int cf = 0; cf < 4; ++cf)
        #pragma unroll
        for (int r = 0; r < 4; ++r) {
          s[cf][r] = __expf(s[cf][r] - m[r]);
          lsum[r] += s[cf][r];
        }

      // ---- P (C-layout) -> per-wave LDS (rotated chunks) -> A-fragments
      unsigned short* pw = &Ps[wave][0];
      #pragma unroll
      for (int cf = 0; cf < 4; ++cf)
        #pragma unroll
        for (int r = 0; r < 4; ++r) {
          int rr = lg * 4 + r;
          int c  = cf * 16 + ll;
          pw[p_addr(rr, c >> 3) + (c & 7)] = f2bf(s[cf][r]);
        }
      bf16x8 pa[2];
      #pragma unroll
      for (int ks = 0; ks < 2; ++ks)
        pa[ks] = *reinterpret_cast<const bf16x8*>(&pw[p_addr(ll, ks * 4 + lg)]);

      // ---- PV
      const unsigned short* Vc = &Vs[cur][0];
      #pragma unroll
      for (int ds = 0; ds < 8; ++ds) {
        bf16x8 vf[2];
        #pragma unroll
        for (int ks = 0; ks < 2; ++ks) {
          int dl = ds * 16 + ll;
          int cc = (ks * 4 + lg) ^ (dl & 7);
          vf[ks] = *reinterpret_cast<const bf16x8*>(&Vc[dl * 64 + cc * 8]);
        }
        __builtin_amdgcn_s_setprio(1);
        #pragma unroll
        for (int ks = 0; ks < 2; ++ks)
          of[ds] = __builtin_amdgcn_mfma_f32_16x16x32_bf16(pa[ks], vf[ks], of[ds], 0, 0, 0);
        __builtin_amdgcn_s_setprio(0);
      }

      __syncthreads();   // implicit vmcnt(0) drain completes next-tile staging
      cur ^= 1;
    }

    // ---- epilogue: reduce per-lane partial sums across the 16-lane group
    float inv[4];
    #pragma unroll
    for (int r = 0; r < 4; ++r) {
      float sum = lsum[r];
      #pragma unroll
      for (int msk = 1; msk < 16; msk <<= 1) sum += __shfl_xor(sum, msk);
      inv[r] = 1.f / sum;
    }
    #pragma unroll
    for (int ds = 0; ds < 8; ++ds)
      #pragma unroll
      for (int r = 0; r < 4; ++r) {
        int row = q0 + lg * 4 + r;
        ob[(size_t)row * (NH * DH) + h * DH + ds * 16 + ll] = f2bf(of[ds][r] * inv[r]);
      }
    __syncthreads();   // LDS reuse safety across segments
  }
}

// ---------------------------------------------------------------- launch
extern "C" void kernel_launch(void* const* d_in, const int* in_sizes, int n_in,
                              void* d_out, int out_size, void* d_ws, size_t ws_size,
                              hipStream_t stream) {
  (void)in_sizes; (void)n_in; (void)out_size; (void)ws_size;
  const float* x    = (const float*)d_in[0];
  const float* Wq   = (const float*)d_in[1];
  const float* bq   = (const float*)d_in[2];
  const float* Wk   = (const float*)d_in[3];
  const float* bk   = (const float*)d_in[4];
  const float* Wv   = (const float*)d_in[5];
  const float* bv   = (const float*)d_in[6];
  const float* Wo   = (const float*)d_in[7];
  const float* cosT = (const float*)d_in[8];
  const float* sinT = (const float*)d_in[9];
  // d_in[10] = attention_mask: unused (causal mask computed arithmetically)

  char* ws = (char*)d_ws;
  size_t off = 0;
  auto alloc = [&](size_t bytes) { void* p = ws + off; off += (bytes + 255) & ~(size_t)255; return p; };
  unsigned short* xb     = (unsigned short*)alloc((size_t)L_SEQ * HID * 2);       // x bf16
  unsigned short* Wqkvt  = (unsigned short*)alloc((size_t)NQKV * HID * 2);        // [Wq^T;Wk^T;Wv^T]
  unsigned short* Wot    = (unsigned short*)alloc((size_t)HID * HID * 2);         // Wo^T
  float*          qkvlin = (float*)alloc((size_t)L_SEQ * NQKV * 4);               // fused qkv pre-rope
  unsigned short* qbuf   = (unsigned short*)alloc((size_t)NH * L_SEQ * DH * 2);   // [H][L][D]
  unsigned short* kbuf   = (unsigned short*)alloc((size_t)NKV * L_SEQ * DH * 2);  // [KV][L][D]
  unsigned short* vtb    = (unsigned short*)alloc((size_t)NKV * DH * L_SEQ * 2);  // [KV][D][L]
  unsigned short* attno  = (unsigned short*)qkvlin;  // alias: qkvlin dead after rope/bias

  cast_bf16_kernel<<<(L_SEQ * HID / 4 + 255) / 256, 256, 0, stream>>>(x, xb, L_SEQ * HID / 4);
  transpose_cast_kernel<<<dim3(HID / 32, HID / 32), dim3(32, 8), 0, stream>>>(Wq, Wqkvt, HID, HID);
  transpose_cast_kernel<<<dim3(256 / 32, HID / 32), dim3(32, 8), 0, stream>>>(Wk, Wqkvt + (size_t)4096 * HID, HID, 256);
  transpose_cast_kernel<<<dim3(256 / 32, HID / 32), dim3(32, 8), 0, stream>>>(Wv, Wqkvt + (size_t)4352 * HID, HID, 256);
  transpose_cast_kernel<<<dim3(HID / 32, HID / 32), dim3(32, 8), 0, stream>>>(Wo, Wot, HID, HID);

  gemm_bt_kernel<<<dim3(NQKV / 128, L_SEQ / 128), 256, 0, stream>>>(xb, Wqkvt, qkvlin, L_SEQ, NQKV, HID);

  rope_q_kernel<<<dim3(L_SEQ, NH), 128, 0, stream>>>(qkvlin, bq, cosT, sinT, qbuf);
  rope_k_kernel<<<dim3(L_SEQ, NKV), 128, 0, stream>>>(qkvlin, bk, cosT, sinT, kbuf);
  bias_vt_kernel<<<dim3(L_SEQ, NKV), 128, 0, stream>>>(qkvlin, bv, vtb);

  attn_kernel<<<dim3(16, NH), 256, 0, stream>>>(qbuf, kbuf, vtb, attno);

  gemm_bt_kernel<<<dim3(HID / 128, L_SEQ / 128), 256, 0, stream>>>(attno, Wot, (float*)d_out, L_SEQ, HID, HID);
}

// Round 4
// 433.696 us; speedup vs baseline: 1.5552x; 1.0427x over previous
//
// GLM4 attention block (B=1, L=2048, HID=4096, H=32, KV=2, D=128, ROT=64) on MI355X.
// Round 4: GEMM rebuilt as BM256xBN128xBK32, 4 waves (wave-tile 128x64),
//   dbuf swizzled LDS, issue-early staging, raw s_barrier + explicit vmcnt
//   (no __syncthreads drain), mid-phase barrier, setprio. Attn unchanged (round-3).
#include <hip/hip_runtime.h>
#include <stdint.h>

#define L_SEQ 2048
#define HID   4096
#define NH    32
#define NKV   2
#define DH    128
#define NQKV  4608                     // H*D + 2*KV*D
#define QSCALE 0.088388347648318447f   // 128^-0.5

typedef __bf16 bf16x8 __attribute__((ext_vector_type(8)));
typedef float  f32x4  __attribute__((ext_vector_type(4)));

__device__ __forceinline__ unsigned short f2bf(float f) {
  union { float f; unsigned u; } cv; cv.f = f;
  unsigned u = cv.u;
  return (unsigned short)((u + 0x7fffu + ((u >> 16) & 1u)) >> 16);   // RNE, finite-only
}

// async global->LDS, 16B per lane; LDS dest = wave-uniform base + lane*16
#define GLL16(gsrc, ldst)                                                              \
  __builtin_amdgcn_global_load_lds(                                                    \
      (const __attribute__((address_space(1))) unsigned int*)(gsrc),                   \
      (__attribute__((address_space(3))) unsigned int*)(ldst), 16, 0, 0)

// ---------------------------------------------------------------- casts
__global__ __launch_bounds__(256) void cast_bf16_kernel(const float* __restrict__ in,
                                                        unsigned short* __restrict__ out,
                                                        int n4) {
  int i = blockIdx.x * 256 + threadIdx.x;
  if (i >= n4) return;
  float4 v = reinterpret_cast<const float4*>(in)[i];
  ushort4 o;
  o.x = f2bf(v.x); o.y = f2bf(v.y); o.z = f2bf(v.z); o.w = f2bf(v.w);
  reinterpret_cast<ushort4*>(out)[i] = o;
}

// in: (R,C) fp32 row-major -> out: (C,R) bf16 row-major
__global__ __launch_bounds__(256) void transpose_cast_kernel(const float* __restrict__ in,
                                                             unsigned short* __restrict__ out,
                                                             int R, int C) {
  __shared__ float tile[32][33];
  int c0 = blockIdx.x * 32, r0 = blockIdx.y * 32;
  int tx = threadIdx.x, ty = threadIdx.y;
  #pragma unroll
  for (int i = ty; i < 32; i += 8)
    tile[i][tx] = in[(size_t)(r0 + i) * C + (c0 + tx)];
  __syncthreads();
  #pragma unroll
  for (int i = ty; i < 32; i += 8)
    out[(size_t)(c0 + i) * R + (r0 + tx)] = f2bf(tile[tx][i]);
}

// ---------------------------------------------------------------- GEMM  C(M,N) = A(M,K) * Bt(N,K)^T
// BM=256, BN=128, BK=32; 4 waves, wave-tile 128x64 (8x4 16x16 frags);
// double-buffered swizzled LDS (48KB); issue-early staging; raw barriers.
#define GBM 256
#define GBN 128
#define GBK 32

__global__ __launch_bounds__(256, 2) void gemm256_kernel(const unsigned short* __restrict__ A,
                                                         const unsigned short* __restrict__ Bt,
                                                         float* __restrict__ C,
                                                         int M, int N, int K) {
  __shared__ __attribute__((aligned(16))) unsigned short As[2][GBM * GBK];
  __shared__ __attribute__((aligned(16))) unsigned short Bs[2][GBN * GBK];
  const int tid = threadIdx.x;
  const int wave = tid >> 6, lane = tid & 63;
  const int lg = lane >> 4, ll = lane & 15;
  const int wm = wave >> 1, wn = wave & 1;     // 2x2 wave grid, 128x64 each

  // XCD-chunked block swizzle (bijective when nwg%8==0)
  int gx = gridDim.x, nwg = gx * gridDim.y;
  int flat = blockIdx.y * gx + blockIdx.x;
  int bx = blockIdx.x, by = blockIdx.y;
  if ((nwg & 7) == 0) {
    int t = (flat & 7) * (nwg >> 3) + (flat >> 3);
    bx = t % gx; by = t / gx;
  }
  const int m0 = by * GBM, n0 = bx * GBN;

  f32x4 acc[8][4] = {};
  const int NT = K >> 5;   // K / 32

  // staging: A tile 256x32 = 1024 chunks (4/wave-lane-issue), B 128x32 = 512 (2/wave)
  // row has 4 chunks of 16B; physical chunk c holds global chunk c ^ swz(row),
  // swz(row) = (row ^ (row>>2)) & 3  -> 2-way max on frag reads (free).
  auto stage = [&](int t, int buf) {
    const int k0 = t * GBK;
    #pragma unroll
    for (int i = 0; i < 4; ++i) {
      int ci  = (wave * 4 + i) * 64 + lane;
      int row = ci >> 2;
      int cg  = (ci & 3) ^ ((row ^ (row >> 2)) & 3);
      GLL16(A + (size_t)(m0 + row) * K + k0 + cg * 8, &As[buf][(wave * 4 + i) * 512]);
    }
    #pragma unroll
    for (int i = 0; i < 2; ++i) {
      int ci  = (wave * 2 + i) * 64 + lane;
      int row = ci >> 2;
      int cg  = (ci & 3) ^ ((row ^ (row >> 2)) & 3);
      GLL16(Bt + (size_t)(n0 + row) * K + k0 + cg * 8, &Bs[buf][(wave * 2 + i) * 512]);
    }
  };

  stage(0, 0);
  asm volatile("s_waitcnt vmcnt(0)" ::: "memory");
  __builtin_amdgcn_s_barrier();
  asm volatile("" ::: "memory");

  for (int t = 0; t < NT; ++t) {
    const int cur = t & 1;
    if (t + 1 < NT) stage(t + 1, cur ^ 1);     // issue-early; waited at iter end

    const unsigned short* Ac = &As[cur][0];
    const unsigned short* Bc = &Bs[cur][0];

    // phase 0: B frags + A frags 0..3, 16 MFMA
    bf16x8 bfr[4];
    #pragma unroll
    for (int j = 0; j < 4; ++j) {
      int row = wn * 64 + j * 16 + ll;
      bfr[j] = *reinterpret_cast<const bf16x8*>(
          &Bc[row * 32 + ((lg ^ ((row ^ (row >> 2)) & 3)) * 8)]);
    }
    bf16x8 afr[4];
    #pragma unroll
    for (int i = 0; i < 4; ++i) {
      int row = wm * 128 + i * 16 + ll;
      afr[i] = *reinterpret_cast<const bf16x8*>(
          &Ac[row * 32 + ((lg ^ ((row ^ (row >> 2)) & 3)) * 8)]);
    }
    __builtin_amdgcn_s_setprio(1);
    #pragma unroll
    for (int i = 0; i < 4; ++i)
      #pragma unroll
      for (int j = 0; j < 4; ++j)
        acc[i][j] = __builtin_amdgcn_mfma_f32_16x16x32_bf16(afr[i], bfr[j], acc[i][j], 0, 0, 0);
    __builtin_amdgcn_s_setprio(0);
    __builtin_amdgcn_s_barrier();              // mid-phase role-split barrier

    // phase 1: A frags 4..7, 16 MFMA
    bf16x8 afr2[4];
    #pragma unroll
    for (int i = 0; i < 4; ++i) {
      int row = wm * 128 + (i + 4) * 16 + ll;
      afr2[i] = *reinterpret_cast<const bf16x8*>(
          &Ac[row * 32 + ((lg ^ ((row ^ (row >> 2)) & 3)) * 8)]);
    }
    __builtin_amdgcn_s_setprio(1);
    #pragma unroll
    for (int i = 0; i < 4; ++i)
      #pragma unroll
      for (int j = 0; j < 4; ++j)
        acc[i + 4][j] = __builtin_amdgcn_mfma_f32_16x16x32_bf16(afr2[i], bfr[j], acc[i + 4][j], 0, 0, 0);
    __builtin_amdgcn_s_setprio(0);

    // end of iter: own prefetch retired + cross-wave visible; buf cur free for t+2
    asm volatile("s_waitcnt vmcnt(0)" ::: "memory");
    __builtin_amdgcn_s_barrier();
    asm volatile("" ::: "memory");
  }

  #pragma unroll
  for (int i = 0; i < 8; ++i)
    #pragma unroll
    for (int j = 0; j < 4; ++j) {
      int col  = n0 + wn * 64 + j * 16 + ll;
      int rowb = m0 + wm * 128 + i * 16 + lg * 4;
      #pragma unroll
      for (int r = 0; r < 4; ++r)
        C[(size_t)(rowb + r) * N + col] = acc[i][j][r];
    }
}

// ---------------------------------------------------------------- bias + RoPE + relayout
// qkv: [L][4608] fp32. cols 0..4095 = Q, 4096..4351 = K, 4352..4607 = V.
__global__ __launch_bounds__(128) void rope_q_kernel(const float* __restrict__ qkv,
                                                     const float* __restrict__ bq,
                                                     const float* __restrict__ cosT,
                                                     const float* __restrict__ sinT,
                                                     unsigned short* __restrict__ qb) {
  int l = blockIdx.x, h = blockIdx.y, d = threadIdx.x;
  size_t base = (size_t)l * NQKV + h * DH;
  float v = qkv[base + d] + bq[h * DH + d];
  float o;
  if (d < 32) {
    float x2 = qkv[base + d + 32] + bq[h * DH + d + 32];
    o = v * cosT[l * 32 + d] - x2 * sinT[l * 32 + d];
  } else if (d < 64) {
    int i = d - 32;
    float x1 = qkv[base + i] + bq[h * DH + i];
    o = v * cosT[l * 32 + i] + x1 * sinT[l * 32 + i];
  } else {
    o = v;
  }
  qb[((size_t)h * L_SEQ + l) * DH + d] = f2bf(o * QSCALE);
}

__global__ __launch_bounds__(128) void rope_k_kernel(const float* __restrict__ qkv,
                                                     const float* __restrict__ bk,
                                                     const float* __restrict__ cosT,
                                                     const float* __restrict__ sinT,
                                                     unsigned short* __restrict__ kb) {
  int l = blockIdx.x, g = blockIdx.y, d = threadIdx.x;
  size_t base = (size_t)l * NQKV + 4096 + g * DH;
  float v = qkv[base + d] + bk[g * DH + d];
  float o;
  if (d < 32) {
    float x2 = qkv[base + d + 32] + bk[g * DH + d + 32];
    o = v * cosT[l * 32 + d] - x2 * sinT[l * 32 + d];
  } else if (d < 64) {
    int i = d - 32;
    float x1 = qkv[base + i] + bk[g * DH + i];
    o = v * cosT[l * 32 + i] + x1 * sinT[l * 32 + i];
  } else {
    o = v;
  }
  kb[((size_t)g * L_SEQ + l) * DH + d] = f2bf(o);
}

// V stored transposed: vt[g][d][l]
__global__ __launch_bounds__(128) void bias_vt_kernel(const float* __restrict__ qkv,
                                                      const float* __restrict__ bv,
                                                      unsigned short* __restrict__ vt) {
  int l = blockIdx.x, g = blockIdx.y, d = threadIdx.x;
  float o = qkv[(size_t)l * NQKV + 4352 + g * DH + d] + bv[g * DH + d];
  vt[((size_t)g * DH + d) * L_SEQ + l] = f2bf(o);
}

// ---------------------------------------------------------------- flash attention
// grid (16, H); 256 threads = 4 waves. Causal fold-pairing: block pair p handles
// q-tiles p and 31-p (QB=64) sequentially -> uniform 33 KV-tiles per block.
__device__ __forceinline__ int p_addr(int row, int chunk) {
  return row * 72 + (((chunk + row + (row >> 2)) & 7) * 8);
}

__global__ __launch_bounds__(256) void attn_kernel(const unsigned short* __restrict__ qg,
                                                   const unsigned short* __restrict__ kb,
                                                   const unsigned short* __restrict__ vt,
                                                   unsigned short* __restrict__ ob) {
  __shared__ __attribute__((aligned(16))) unsigned short Ks[2][64 * 128];
  __shared__ __attribute__((aligned(16))) unsigned short Vs[2][128 * 64];
  __shared__ __attribute__((aligned(16))) unsigned short Ps[4][16 * 72];

  const int pair = blockIdx.x, h = blockIdx.y;
  const int g = h >> 4;                         // 16 q-heads per kv-head
  const int tid = threadIdx.x, wave = tid >> 6, lane = tid & 63;
  const int lg = lane >> 4, ll = lane & 15;

  const int krow = (lane >> 4);
  const int kcg0 = (lane & 15);
  const int vrow = (lane >> 3);
  const int vcg0 = (lane & 7);

  #pragma unroll
  for (int seg = 0; seg < 2; ++seg) {
    const int qt = seg ? (31 - pair) : pair;
    const int q0 = qt * 64 + wave * 16;

    bf16x8 qf[4];
    #pragma unroll
    for (int f = 0; f < 4; ++f)
      qf[f] = *reinterpret_cast<const bf16x8*>(
          qg + ((size_t)h * L_SEQ + q0 + ll) * DH + f * 32 + lg * 8);

    f32x4 of[8] = {};
    float m[4]  = {-1e30f, -1e30f, -1e30f, -1e30f};
    float lsum[4] = {0.f, 0.f, 0.f, 0.f};

    const int kvN = qt + 1;
    int cur = 0;

    #pragma unroll
    for (int c = 0; c < 4; ++c) {
      int issue = wave * 4 + c;
      int rk = issue * 4 + krow;
      GLL16(kb + ((size_t)g * L_SEQ + rk) * DH + (kcg0 ^ (rk & 7)) * 8, &Ks[0][issue * 512]);
      int rv = issue * 8 + vrow;
      GLL16(vt + ((size_t)g * DH + rv) * L_SEQ + (vcg0 ^ (rv & 7)) * 8, &Vs[0][issue * 512]);
    }
    __syncthreads();

    for (int t = 0; t < kvN; ++t) {
      if (t + 1 < kvN) {
        int kv1 = (t + 1) * 64;
        #pragma unroll
        for (int c = 0; c < 4; ++c) {
          int issue = wave * 4 + c;
          int rk = issue * 4 + krow;
          GLL16(kb + ((size_t)g * L_SEQ + kv1 + rk) * DH + (kcg0 ^ (rk & 7)) * 8,
                &Ks[cur ^ 1][issue * 512]);
          int rv = issue * 8 + vrow;
          GLL16(vt + ((size_t)g * DH + rv) * L_SEQ + kv1 + (vcg0 ^ (rv & 7)) * 8,
                &Vs[cur ^ 1][issue * 512]);
        }
      }

      f32x4 s[4] = {};
      const unsigned short* Kc = &Ks[cur][0];
      #pragma unroll
      for (int cf = 0; cf < 4; ++cf) {
        bf16x8 kf[4];
        #pragma unroll
        for (int f = 0; f < 4; ++f) {
          int rk = cf * 16 + ll;
          int cc = (f * 4 + lg) ^ (rk & 7);
          kf[f] = *reinterpret_cast<const bf16x8*>(&Kc[rk * 128 + cc * 8]);
        }
        __builtin_amdgcn_s_setprio(1);
        #pragma unroll
        for (int f = 0; f < 4; ++f)
          s[cf] = __builtin_amdgcn_mfma_f32_16x16x32_bf16(qf[f], kf[f], s[cf], 0, 0, 0);
        __builtin_amdgcn_s_setprio(0);
      }

      if (t == qt) {
        #pragma unroll
        for (int cf = 0; cf < 4; ++cf)
          #pragma unroll
          for (int r = 0; r < 4; ++r)
            if (cf * 16 + ll > wave * 16 + lg * 4 + r) s[cf][r] = -1e30f;
      }

      float pmax[4];
      #pragma unroll
      for (int r = 0; r < 4; ++r)
        pmax[r] = fmaxf(fmaxf(s[0][r], s[1][r]), fmaxf(s[2][r], s[3][r]));
      bool ok = true;
      #pragma unroll
      for (int r = 0; r < 4; ++r) ok = ok && (pmax[r] - m[r] <= 8.f);
      if (!__all(ok)) {
        float alpha[4];
        #pragma unroll
        for (int r = 0; r < 4; ++r) {
          float mx = pmax[r];
          #pragma unroll
          for (int msk = 1; msk < 16; msk <<= 1) mx = fmaxf(mx, __shfl_xor(mx, msk));
          float mnew = fmaxf(m[r], mx);
          alpha[r] = __expf(m[r] - mnew);
          m[r] = mnew;
          lsum[r] *= alpha[r];
        }
        #pragma unroll
        for (int ds = 0; ds < 8; ++ds)
          #pragma unroll
          for (int r = 0; r < 4; ++r)
            of[ds][r] *= alpha[r];
      }
      #pragma unroll
      for (int cf = 0; cf < 4; ++cf)
        #pragma unroll
        for (int r = 0; r < 4; ++r) {
          s[cf][r] = __expf(s[cf][r] - m[r]);
          lsum[r] += s[cf][r];
        }

      unsigned short* pw = &Ps[wave][0];
      #pragma unroll
      for (int cf = 0; cf < 4; ++cf)
        #pragma unroll
        for (int r = 0; r < 4; ++r) {
          int rr = lg * 4 + r;
          int c  = cf * 16 + ll;
          pw[p_addr(rr, c >> 3) + (c & 7)] = f2bf(s[cf][r]);
        }
      bf16x8 pa[2];
      #pragma unroll
      for (int ks = 0; ks < 2; ++ks)
        pa[ks] = *reinterpret_cast<const bf16x8*>(&pw[p_addr(ll, ks * 4 + lg)]);

      const unsigned short* Vc = &Vs[cur][0];
      #pragma unroll
      for (int ds = 0; ds < 8; ++ds) {
        bf16x8 vf[2];
        #pragma unroll
        for (int ks = 0; ks < 2; ++ks) {
          int dl = ds * 16 + ll;
          int cc = (ks * 4 + lg) ^ (dl & 7);
          vf[ks] = *reinterpret_cast<const bf16x8*>(&Vc[dl * 64 + cc * 8]);
        }
        __builtin_amdgcn_s_setprio(1);
        #pragma unroll
        for (int ks = 0; ks < 2; ++ks)
          of[ds] = __builtin_amdgcn_mfma_f32_16x16x32_bf16(pa[ks], vf[ks], of[ds], 0, 0, 0);
        __builtin_amdgcn_s_setprio(0);
      }

      __syncthreads();
      cur ^= 1;
    }

    float inv[4];
    #pragma unroll
    for (int r = 0; r < 4; ++r) {
      float sum = lsum[r];
      #pragma unroll
      for (int msk = 1; msk < 16; msk <<= 1) sum += __shfl_xor(sum, msk);
      inv[r] = 1.f / sum;
    }
    #pragma unroll
    for (int ds = 0; ds < 8; ++ds)
      #pragma unroll
      for (int r = 0; r < 4; ++r) {
        int row = q0 + lg * 4 + r;
        ob[(size_t)row * (NH * DH) + h * DH + ds * 16 + ll] = f2bf(of[ds][r] * inv[r]);
      }
    __syncthreads();
  }
}

// ---------------------------------------------------------------- launch
extern "C" void kernel_launch(void* const* d_in, const int* in_sizes, int n_in,
                              void* d_out, int out_size, void* d_ws, size_t ws_size,
                              hipStream_t stream) {
  (void)in_sizes; (void)n_in; (void)out_size; (void)ws_size;
  const float* x    = (const float*)d_in[0];
  const float* Wq   = (const float*)d_in[1];
  const float* bq   = (const float*)d_in[2];
  const float* Wk   = (const float*)d_in[3];
  const float* bk   = (const float*)d_in[4];
  const float* Wv   = (const float*)d_in[5];
  const float* bv   = (const float*)d_in[6];
  const float* Wo   = (const float*)d_in[7];
  const float* cosT = (const float*)d_in[8];
  const float* sinT = (const float*)d_in[9];
  // d_in[10] = attention_mask: unused (causal mask computed arithmetically)

  char* ws = (char*)d_ws;
  size_t off = 0;
  auto alloc = [&](size_t bytes) { void* p = ws + off; off += (bytes + 255) & ~(size_t)255; return p; };
  unsigned short* xb     = (unsigned short*)alloc((size_t)L_SEQ * HID * 2);
  unsigned short* Wqkvt  = (unsigned short*)alloc((size_t)NQKV * HID * 2);
  unsigned short* Wot    = (unsigned short*)alloc((size_t)HID * HID * 2);
  float*          qkvlin = (float*)alloc((size_t)L_SEQ * NQKV * 4);
  unsigned short* qbuf   = (unsigned short*)alloc((size_t)NH * L_SEQ * DH * 2);
  unsigned short* kbuf   = (unsigned short*)alloc((size_t)NKV * L_SEQ * DH * 2);
  unsigned short* vtb    = (unsigned short*)alloc((size_t)NKV * DH * L_SEQ * 2);
  unsigned short* attno  = (unsigned short*)qkvlin;  // alias: qkvlin dead after rope/bias

  cast_bf16_kernel<<<(L_SEQ * HID / 4 + 255) / 256, 256, 0, stream>>>(x, xb, L_SEQ * HID / 4);
  transpose_cast_kernel<<<dim3(HID / 32, HID / 32), dim3(32, 8), 0, stream>>>(Wq, Wqkvt, HID, HID);
  transpose_cast_kernel<<<dim3(256 / 32, HID / 32), dim3(32, 8), 0, stream>>>(Wk, Wqkvt + (size_t)4096 * HID, HID, 256);
  transpose_cast_kernel<<<dim3(256 / 32, HID / 32), dim3(32, 8), 0, stream>>>(Wv, Wqkvt + (size_t)4352 * HID, HID, 256);
  transpose_cast_kernel<<<dim3(HID / 32, HID / 32), dim3(32, 8), 0, stream>>>(Wo, Wot, HID, HID);

  gemm256_kernel<<<dim3(NQKV / GBN, L_SEQ / GBM), 256, 0, stream>>>(xb, Wqkvt, qkvlin, L_SEQ, NQKV, HID);

  rope_q_kernel<<<dim3(L_SEQ, NH), 128, 0, stream>>>(qkvlin, bq, cosT, sinT, qbuf);
  rope_k_kernel<<<dim3(L_SEQ, NKV), 128, 0, stream>>>(qkvlin, bk, cosT, sinT, kbuf);
  bias_vt_kernel<<<dim3(L_SEQ, NKV), 128, 0, stream>>>(qkvlin, bv, vtb);

  attn_kernel<<<dim3(16, NH), 256, 0, stream>>>(qbuf, kbuf, vtb, attno);

  gemm256_kernel<<<dim3(HID / GBN, L_SEQ / GBM), 256, 0, stream>>>(attno, Wot, (float*)d_out, L_SEQ, HID, HID);
}